// Round 1
// 738.502 us; speedup vs baseline: 1.1182x; 1.1182x over previous
//
#include <hip/hip_runtime.h>
#include <hip/hip_bf16.h>

// x: (R=64, C=256, B=4, E=768) fp32 ; query: (Q=256, B=4, QD=512)
// Wq: (768,512), Wk/Wv/Wo: (768,768), biases: (768,)  ; out: (R,C,B,E) fp32
// H=12, D=64, scaling = D^-0.5/sqrt(Q) = 1/128
//
// Decomposition:
//  xsum[rb,e]   = sum_c x[r,c,n,e]                       (rb = r*4+n)
//  ksum[rb,e]   = xsum @ Wk^T + 256*bk
//  qp[qb,e]     = (query @ Wq^T + bq) / 128              (qb = q*4+n)
//  psum[h,n,r]  = sum_q softmax_r( qp . ksum )
//  vtmp[m,e]    = bf16( (x @ Wv^T + bv) * psum[e>>6, m&3, m>>10] )
//  out[m,f]     = vtmp @ Wo^T + bo
// The two 65536x768x768 GEMMs run on a 256x256-tile, BK=32, 8-wave MFMA kernel
// with a 3-deep counted-vmcnt global_load_lds pipeline + swizzled LDS (T2/T3/T4/T5)
// and XCD-aware block swizzle (T1).

typedef __attribute__((ext_vector_type(8))) short bf16x8;
typedef __attribute__((ext_vector_type(4))) float f32x4;

__device__ __forceinline__ void load_lds16(const void* g, void* l) {
    __builtin_amdgcn_global_load_lds(
        (const __attribute__((address_space(1))) void*)g,
        (__attribute__((address_space(3))) void*)l, 16, 0, 0);
}

// ---- pass 1: column-sum of x over c (4 c-partials) + fused fp32->bf16 of x ----
// thread handles 4 consecutive e over 64 c's. float4 loads, ushort4 stores.
__global__ __launch_bounds__(256) void xsum_cvt_kernel(const float* __restrict__ x,
                                                       float* __restrict__ xsp,
                                                       __hip_bfloat16* __restrict__ xb) {
    int gid = blockIdx.x * 256 + threadIdx.x;   // 0 .. 196607
    int e4 = gid % 192;                          // e / 4
    int t2 = gid / 192;                          // 0 .. 1023
    int rb = t2 & 255;                           // r*4+n
    int part = t2 >> 8;                          // c-chunk 0..3
    int r = rb >> 2, n = rb & 3;
    size_t base = (size_t)r * 786432 + (size_t)part * 196608 + n * 768 + e4 * 4;
    const float4* px = (const float4*)(x + base);
    ushort* xbu = (ushort*)xb + base;
    float4 s = {0.f, 0.f, 0.f, 0.f};
    #pragma unroll 4
    for (int c = 0; c < 64; ++c) {
        float4 v = px[(size_t)c * 768];
        s.x += v.x; s.y += v.y; s.z += v.z; s.w += v.w;
        union { ushort4 u; __hip_bfloat16 h[4]; } pk;
        pk.h[0] = __float2bfloat16(v.x); pk.h[1] = __float2bfloat16(v.y);
        pk.h[2] = __float2bfloat16(v.z); pk.h[3] = __float2bfloat16(v.w);
        *(ushort4*)(xbu + (size_t)c * 3072) = pk.u;
    }
    *(float4*)(xsp + (size_t)part * 196608 + rb * 768 + e4 * 4) = s;
}

// ---- small fp32->bf16 conversion (weights) ----
__global__ __launch_bounds__(256) void f2b_kernel(const float* __restrict__ in,
                                                  __hip_bfloat16* __restrict__ out, int n4) {
    int i = blockIdx.x * 256 + threadIdx.x;
    if (i < n4) {
        float4 v = ((const float4*)in)[i];
        out[i * 4 + 0] = __float2bfloat16(v.x);
        out[i * 4 + 1] = __float2bfloat16(v.y);
        out[i * 4 + 2] = __float2bfloat16(v.z);
        out[i * 4 + 3] = __float2bfloat16(v.w);
    }
}

// ---- small fp32 GEMM (ksum / qp): Cf = epilogue(A(MxK) @ W(NxK)^T) ----
// MODE 0: A is 4 c-partials (stride 196608) summed on load; Cf = acc + p0*bias[n]
// MODE 1: Cf = (acc + bias[n]) * p0
template <int MODE>
__global__ __launch_bounds__(256) void gemm_kernel(const float* __restrict__ A,
                                                   const float* __restrict__ W,
                                                   const float* __restrict__ bias,
                                                   float* __restrict__ Cf,
                                                   int M, int N, int K, float p0) {
    __shared__ float As[16][65];
    __shared__ float Ws[16][65];
    int tid = threadIdx.x;
    int tx = tid & 15, ty = tid >> 4;
    int m0 = blockIdx.y * 64, n0 = blockIdx.x * 64;
    float acc[4][4] = {};

    for (int k0 = 0; k0 < K; k0 += 16) {
        #pragma unroll
        for (int i = 0; i < 4; ++i) {
            int idx = tid + 256 * i;
            int mm = idx >> 4, kk = idx & 15;
            size_t ai = (size_t)(m0 + mm) * K + k0 + kk;
            if (MODE == 0)
                As[kk][mm] = A[ai] + A[ai + 196608] + A[ai + 393216] + A[ai + 589824];
            else
                As[kk][mm] = A[ai];
            Ws[kk][mm] = W[(size_t)(n0 + mm) * K + k0 + kk];
        }
        __syncthreads();
        #pragma unroll
        for (int kk = 0; kk < 16; ++kk) {
            float a[4], b[4];
            #pragma unroll
            for (int i = 0; i < 4; ++i) a[i] = As[kk][ty + 16 * i];
            #pragma unroll
            for (int j = 0; j < 4; ++j) b[j] = Ws[kk][tx + 16 * j];
            #pragma unroll
            for (int i = 0; i < 4; ++i)
                #pragma unroll
                for (int j = 0; j < 4; ++j) acc[i][j] += a[i] * b[j];
        }
        __syncthreads();
    }
    #pragma unroll
    for (int i = 0; i < 4; ++i) {
        int m = m0 + ty + 16 * i;
        #pragma unroll
        for (int j = 0; j < 4; ++j) {
            int n = n0 + tx + 16 * j;
            float v = acc[i][j];
            if (MODE == 0) Cf[(size_t)m * N + n] = v + p0 * bias[n];
            else           Cf[(size_t)m * N + n] = (v + bias[n]) * p0;
        }
    }
}

// ---- attention: scores + softmax over r + column-sum of probs ----
__global__ __launch_bounds__(256) void attn_kernel(const float* __restrict__ qp,
                                                   const float* __restrict__ ksum,
                                                   float* __restrict__ psum) {
    int h = blockIdx.x >> 2;
    int n = blockIdx.x & 3;
    __shared__ float kd[64][65];
    __shared__ float sacc[4][64];
    int tid = threadIdx.x;

    #pragma unroll
    for (int it = 0; it < 16; ++it) {
        int idx = tid + 256 * it;
        int r = idx >> 6, d = idx & 63;
        kd[r][d] = ksum[(size_t)(r * 4 + n) * 768 + h * 64 + d];
    }
    __syncthreads();

    int wave = tid >> 6, lane = tid & 63;
    float acc = 0.f;
    for (int q = wave; q < 256; q += 4) {
        float qv = qp[(size_t)(q * 4 + n) * 768 + h * 64 + lane];
        float val = 0.f;
        #pragma unroll
        for (int d = 0; d < 64; ++d) val += __shfl(qv, d) * kd[lane][d];
        float mx = val;
        #pragma unroll
        for (int off = 1; off < 64; off <<= 1) mx = fmaxf(mx, __shfl_xor(mx, off));
        float p = __expf(val - mx);
        float s = p;
        #pragma unroll
        for (int off = 1; off < 64; off <<= 1) s += __shfl_xor(s, off);
        acc += p / s;
    }
    sacc[wave][lane] = acc;
    __syncthreads();
    if (tid < 64) {
        psum[blockIdx.x * 64 + tid] =
            sacc[0][tid] + sacc[1][tid] + sacc[2][tid] + sacc[3][tid];
    }
}

// ---- MFMA bf16 GEMM v2: 256x256 tile, BK=32, 8 waves (2Mx4N), 512 threads ----
// 3-slot LDS pipeline (96 KB), counted vmcnt(4) (1 tile in flight across the
// per-tile barrier, prefetch issued 2 tiles ahead), XOR-swizzled LDS applied as
// pre-swizzled global source + swizzled ds_read (rule 21), setprio around MFMA
// clusters, XCD-aware block swizzle.
// Per wave: 128x64 output = acc[8][4] f32x4. Per tile: 2 phases x 16 MFMA.
// MODE 2: Cb = bf16((acc + bias[n]) * scale[((n>>6)*4 + (m&3))*64 + (m>>10)])
// MODE 3: Cf = acc + bias[n]

// physical short-offset of logical (row R, k-group kg) inside one 256x32 tile:
// row-pair = R>>1 (128 B each, spans all 32 banks); 16B-slot within pair is
// XOR-swizzled by pair&7 -> ds_read_b128 conflict-free (2 lanes / 4-bank group).
__device__ __forceinline__ int swz(int R, int kg) {
    return ((R >> 1) << 6) + ((((((R & 1) << 2) | kg)) ^ ((R >> 1) & 7)) << 3);
}

template <int MODE>
__global__ __launch_bounds__(512, 2) void mfma_gemm2(const ushort* __restrict__ A,
                                                     const ushort* __restrict__ W,
                                                     const float* __restrict__ bias,
                                                     const float* __restrict__ scale,
                                                     float* __restrict__ Cf,
                                                     __hip_bfloat16* __restrict__ Cb,
                                                     int M, int N, int K) {
    __shared__ short lds[49152];        // 3 slots x (A 8192 + B 8192 shorts) = 96 KB
    const int NT = K >> 5;              // K-tiles of 32
    int tid = threadIdx.x;
    int wave = tid >> 6, lane = tid & 63;
    int wr = wave >> 2, wc = wave & 3;  // 2 x 4 wave grid
    int r16 = lane & 15, kg = lane >> 4;

    // T1: XCD-aware block swizzle (gridDim.x % 8 == 0 -> bijective)
    int cpx = gridDim.x >> 3;
    int h = blockIdx.x;
    int orig = (h & 7) * cpx + (h >> 3);
    int nbx = N >> 8;
    int by = orig / nbx, bx = orig - by * nbx;
    int m0 = by << 8, n0 = bx << 8;

    // staging: 1024 chunks of 16B per 256x32 tile; thread owns chunks tid, tid+512.
    // LDS deposit is linear (wave-uniform base + lane*16); the swizzle is applied
    // by permuting the GLOBAL source (inverse == same XOR involution).
    int c0 = tid, c1 = tid + 512;
    int p0c = c0 >> 3, s0c = (c0 & 7) ^ (p0c & 7);
    int row0 = (p0c << 1) | (s0c >> 2), kg0 = s0c & 3;
    int p1c = c1 >> 3, s1c = (c1 & 7) ^ (p1c & 7);
    int row1 = (p1c << 1) | (s1c >> 2), kg1 = s1c & 3;
    const ushort* pA0 = A + (size_t)(m0 + row0) * K + kg0 * 8;
    const ushort* pA1 = A + (size_t)(m0 + row1) * K + kg1 * 8;
    const ushort* pB0 = W + (size_t)(n0 + row0) * K + kg0 * 8;
    const ushort* pB1 = W + (size_t)(n0 + row1) * K + kg1 * 8;
    int dep0 = (wave * 64) * 8;         // shorts; chunk range of this wave
    int dep1 = (512 + wave * 64) * 8;

    f32x4 acc[8][4];
    #pragma unroll
    for (int i = 0; i < 8; ++i)
        #pragma unroll
        for (int j = 0; j < 4; ++j) acc[i][j] = (f32x4){0.f, 0.f, 0.f, 0.f};

    // prologue: issue tiles 0 and 1 (4 loads each per wave)
    load_lds16(pA0 + 0, &lds[dep0]);
    load_lds16(pA1 + 0, &lds[dep1]);
    load_lds16(pB0 + 0, &lds[8192 + dep0]);
    load_lds16(pB1 + 0, &lds[8192 + dep1]);
    load_lds16(pA0 + 32, &lds[16384 + dep0]);
    load_lds16(pA1 + 32, &lds[16384 + dep1]);
    load_lds16(pB0 + 32, &lds[16384 + 8192 + dep0]);
    load_lds16(pB1 + 32, &lds[16384 + 8192 + dep1]);

    int s = 0;           // slot of tile t
    int s2b = 2 * 16384; // slot base of tile t+2 (== slot vacated by tile t-1)
    int k2 = 64;         // k0 of tile t+2
    for (int t = 0; t < NT; ++t) {
        // counted wait: tile t's 4 loads are the oldest; t+1's 4 may stay in flight
        if (t + 1 < NT) { asm volatile("s_waitcnt vmcnt(4)" ::: "memory"); }
        else           { asm volatile("s_waitcnt vmcnt(0)" ::: "memory"); }
        __builtin_amdgcn_s_barrier();
        __builtin_amdgcn_sched_barrier(0);
        const short* sb = &lds[s * 16384];

        bf16x8 bv[4], af[4];
        #pragma unroll
        for (int ni = 0; ni < 4; ++ni)
            bv[ni] = *(const bf16x8*)&sb[8192 + swz(wc * 64 + ni * 16 + r16, kg)];
        #pragma unroll
        for (int mi = 0; mi < 4; ++mi)
            af[mi] = *(const bf16x8*)&sb[swz(wr * 128 + mi * 16 + r16, kg)];
        if (t + 2 < NT) {               // stage A-half of tile t+2
            load_lds16(pA0 + k2, &lds[s2b + dep0]);
            load_lds16(pA1 + k2, &lds[s2b + dep1]);
        }
        __builtin_amdgcn_s_setprio(1);
        #pragma unroll
        for (int mi = 0; mi < 4; ++mi)
            #pragma unroll
            for (int ni = 0; ni < 4; ++ni)
                acc[mi][ni] = __builtin_amdgcn_mfma_f32_16x16x32_bf16(
                    af[mi], bv[ni], acc[mi][ni], 0, 0, 0);
        __builtin_amdgcn_s_setprio(0);

        #pragma unroll
        for (int mi = 0; mi < 4; ++mi)
            af[mi] = *(const bf16x8*)&sb[swz(wr * 128 + 64 + mi * 16 + r16, kg)];
        if (t + 2 < NT) {               // stage B-half of tile t+2
            load_lds16(pB0 + k2, &lds[s2b + 8192 + dep0]);
            load_lds16(pB1 + k2, &lds[s2b + 8192 + dep1]);
        }
        __builtin_amdgcn_s_setprio(1);
        #pragma unroll
        for (int mi = 0; mi < 4; ++mi)
            #pragma unroll
            for (int ni = 0; ni < 4; ++ni)
                acc[4 + mi][ni] = __builtin_amdgcn_mfma_f32_16x16x32_bf16(
                    af[mi], bv[ni], acc[4 + mi][ni], 0, 0, 0);
        __builtin_amdgcn_s_setprio(0);

        s = (s == 2) ? 0 : s + 1;
        s2b = (s2b == 2 * 16384) ? 0 : s2b + 16384;
        k2 += 32;
    }

    // epilogue: C/D layout col=lane&15, row=(lane>>4)*4+i
    int col = lane & 15, rbase = (lane >> 4) << 2;
    #pragma unroll
    for (int ni = 0; ni < 4; ++ni) {
        int gn = n0 + wc * 64 + ni * 16 + col;
        float bn = bias[gn];
        #pragma unroll
        for (int mi = 0; mi < 8; ++mi) {
            int gmb = m0 + wr * 128 + mi * 16 + rbase;
            #pragma unroll
            for (int i = 0; i < 4; ++i) {
                int gm = gmb + i;
                float v = acc[mi][ni][i] + bn;
                if (MODE == 2) {
                    float sc = scale[(((gn >> 6) << 2) + (gm & 3)) * 64 + (gm >> 10)];
                    Cb[(size_t)gm * N + gn] = __float2bfloat16(v * sc);
                } else {
                    Cf[(size_t)gm * N + gn] = v;
                }
            }
        }
    }
}

extern "C" void kernel_launch(void* const* d_in, const int* in_sizes, int n_in,
                              void* d_out, int out_size, void* d_ws, size_t ws_size,
                              hipStream_t stream) {
    const float* x     = (const float*)d_in[0];
    const float* query = (const float*)d_in[1];
    const float* Wq    = (const float*)d_in[2];
    const float* bq    = (const float*)d_in[3];
    const float* Wk    = (const float*)d_in[4];
    const float* bk    = (const float*)d_in[5];
    const float* Wv    = (const float*)d_in[6];
    const float* bv    = (const float*)d_in[7];
    const float* Wo    = (const float*)d_in[8];
    const float* bo    = (const float*)d_in[9];
    float* out = (float*)d_out;

    // workspace layout (~208 MB)
    __hip_bfloat16* xb   = (__hip_bfloat16*)d_ws;        // 65536*768
    __hip_bfloat16* vtmp = xb + 50331648;                // 65536*768
    __hip_bfloat16* Wvb  = vtmp + 50331648;              // 768*768
    __hip_bfloat16* Wob  = Wvb + 589824;                 // 768*768
    float* xsum = (float*)(Wob + 589824);                // (unused, kept for layout)
    float* ksum = xsum + 196608;                         // 256*768
    float* qp   = ksum + 196608;                         // 1024*768
    float* psum = qp + 786432;                           // 12*4*64
    // xsum c-partials (4 x 256 x 768 fp32 = 3 MB) live in the vtmp region:
    // dead until mfma_gemm2<2> runs, consumed by gemm_kernel<0> before that.
    float* xsp = (float*)vtmp;

    // 1) column-sum partials of x over c + x -> bf16 (vectorized, 12 waves/CU)
    xsum_cvt_kernel<<<768, 256, 0, stream>>>(x, xsp, xb);
    // 1b) weights -> bf16
    f2b_kernel<<<576, 256, 0, stream>>>(Wv, Wvb, 147456);
    f2b_kernel<<<576, 256, 0, stream>>>(Wo, Wob, 147456);
    // 2) ksum = (sum_p xsp) @ Wk^T + 256*bk   (256 x 768 x 768)
    gemm_kernel<0><<<dim3(12, 4), 256, 0, stream>>>(xsp, Wk, bk, ksum, 256, 768, 768, 256.0f);
    // 3) qp = (query @ Wq^T + bq) / 128       (1024 x 768 x 512)
    gemm_kernel<1><<<dim3(12, 16), 256, 0, stream>>>(query, Wq, bq, qp, 1024, 768, 512, 0.0078125f);
    // 4) psum = sum_q softmax_r(qp . ksum)
    attn_kernel<<<48, 256, 0, stream>>>(qp, ksum, psum);
    // 5) vtmp = bf16((xb @ Wvb^T + bv) * psum)   MFMA  (65536 x 768 x 768)
    mfma_gemm2<2><<<768, 512, 0, stream>>>(
        (const ushort*)xb, (const ushort*)Wvb, bv, psum, nullptr, vtmp, 65536, 768, 768);
    // 6) out = vtmp @ Wob^T + bo                 MFMA  (65536 x 768 x 768)
    mfma_gemm2<3><<<768, 512, 0, stream>>>(
        (const ushort*)vtmp, (const ushort*)Wob, bo, nullptr, out, nullptr, 65536, 768, 768);
}

// Round 2
// 677.769 us; speedup vs baseline: 1.2184x; 1.0896x over previous
//
#include <hip/hip_runtime.h>
#include <hip/hip_bf16.h>

// x: (R=64, C=256, B=4, E=768) fp32 ; query: (Q=256, B=4, QD=512)
// Wq: (768,512), Wk/Wv/Wo: (768,768), biases: (768,)  ; out: (R,C,B,E) fp32
// H=12, D=64, scaling = D^-0.5/sqrt(Q) = 1/128
//
// Decomposition:
//  xsum[rb,e]   = sum_c x[r,c,n,e]                       (rb = r*4+n)
//  ksum[rb,e]   = xsum @ Wk^T + 256*bk                   (split-K x4)
//  qp[qb,e]     = (query @ Wq^T + bq) / 128              (split-K x2)
//  psum[h,n,r]  = sum_q softmax_r( qp . ksum )
//  vtmp[m,e]    = bf16( (x @ Wv^T + bv) * psum[e>>6, m&3, m>>10] )
//  out[m,f]     = vtmp @ Wo^T + bo
// Big GEMMs: 256x256 tile, BK=32, 8 waves, 4-slot LDS (128KB) counted-vmcnt(8)
// pipeline (prefetch 3 tiles), XOR-swizzled LDS both-sides, setprio, XCD swizzle.

typedef __attribute__((ext_vector_type(8))) short bf16x8;
typedef __attribute__((ext_vector_type(4))) float f32x4;

__device__ __forceinline__ void load_lds16(const void* g, void* l) {
    __builtin_amdgcn_global_load_lds(
        (const __attribute__((address_space(1))) void*)g,
        (__attribute__((address_space(3))) void*)l, 16, 0, 0);
}

// ---- merged prep: xsum partials + x->bf16 (blocks 0..767),
//                   Wv->bf16 (768..1343), Wo->bf16 (1344..1919) ----
__global__ __launch_bounds__(256) void prep_kernel(const float* __restrict__ x,
                                                   float* __restrict__ xsp,
                                                   __hip_bfloat16* __restrict__ xb,
                                                   const float* __restrict__ Wv,
                                                   __hip_bfloat16* __restrict__ Wvb,
                                                   const float* __restrict__ Wo,
                                                   __hip_bfloat16* __restrict__ Wob) {
    int b = blockIdx.x, tid = threadIdx.x;
    if (b < 768) {
        int gid = b * 256 + tid;                 // 0 .. 196607
        int e4 = gid % 192;                      // e / 4
        int t2 = gid / 192;                      // 0 .. 1023
        int rb = t2 & 255;                       // r*4+n
        int part = t2 >> 8;                      // c-chunk 0..3
        int r = rb >> 2, n = rb & 3;
        size_t base = (size_t)r * 786432 + (size_t)part * 196608 + n * 768 + e4 * 4;
        const float4* px = (const float4*)(x + base);
        ushort* xbu = (ushort*)xb + base;
        float4 s = {0.f, 0.f, 0.f, 0.f};
        #pragma unroll 4
        for (int c = 0; c < 64; ++c) {
            float4 v = px[(size_t)c * 768];
            s.x += v.x; s.y += v.y; s.z += v.z; s.w += v.w;
            union { ushort4 u; __hip_bfloat16 h[4]; } pk;
            pk.h[0] = __float2bfloat16(v.x); pk.h[1] = __float2bfloat16(v.y);
            pk.h[2] = __float2bfloat16(v.z); pk.h[3] = __float2bfloat16(v.w);
            *(ushort4*)(xbu + (size_t)c * 3072) = pk.u;
        }
        *(float4*)(xsp + (size_t)part * 196608 + rb * 768 + e4 * 4) = s;
    } else {
        const float* src = (b < 1344) ? Wv : Wo;
        __hip_bfloat16* dst = (b < 1344) ? Wvb : Wob;
        int i = (b - ((b < 1344) ? 768 : 1344)) * 256 + tid;   // 0..147455 float4s
        float4 v = ((const float4*)src)[i];
        dst[i * 4 + 0] = __float2bfloat16(v.x);
        dst[i * 4 + 1] = __float2bfloat16(v.y);
        dst[i * 4 + 2] = __float2bfloat16(v.z);
        dst[i * 4 + 3] = __float2bfloat16(v.w);
    }
}

// ---- small fp32 GEMM with split-K (blockIdx.z): partial z covers K-range
// [z*KS, (z+1)*KS); partial z written to Cf + z*M*N. bias applied in z==0 only.
// MODE 0: A is 4 c-partials (stride 196608) summed on load; +p0*bias
// MODE 1: *p0 epilogue, +bias inside
template <int MODE>
__global__ __launch_bounds__(256) void gemm_kernel(const float* __restrict__ A,
                                                   const float* __restrict__ W,
                                                   const float* __restrict__ bias,
                                                   float* __restrict__ Cf,
                                                   int M, int N, int K, int KS, float p0) {
    __shared__ float As[16][65];
    __shared__ float Ws[16][65];
    int tid = threadIdx.x;
    int tx = tid & 15, ty = tid >> 4;
    int m0 = blockIdx.y * 64, n0 = blockIdx.x * 64;
    int z = blockIdx.z;
    int kbeg = z * KS, kend = kbeg + KS;
    float acc[4][4] = {};

    for (int k0 = kbeg; k0 < kend; k0 += 16) {
        #pragma unroll
        for (int i = 0; i < 4; ++i) {
            int idx = tid + 256 * i;
            int mm = idx >> 4, kk = idx & 15;
            size_t ai = (size_t)(m0 + mm) * K + k0 + kk;
            if (MODE == 0)
                As[kk][mm] = A[ai] + A[ai + 196608] + A[ai + 393216] + A[ai + 589824];
            else
                As[kk][mm] = A[ai];
            Ws[kk][mm] = W[(size_t)(n0 + mm) * K + k0 + kk];
        }
        __syncthreads();
        #pragma unroll
        for (int kk = 0; kk < 16; ++kk) {
            float a[4], b[4];
            #pragma unroll
            for (int i = 0; i < 4; ++i) a[i] = As[kk][ty + 16 * i];
            #pragma unroll
            for (int j = 0; j < 4; ++j) b[j] = Ws[kk][tx + 16 * j];
            #pragma unroll
            for (int i = 0; i < 4; ++i)
                #pragma unroll
                for (int j = 0; j < 4; ++j) acc[i][j] += a[i] * b[j];
        }
        __syncthreads();
    }
    float* Cz = Cf + (size_t)z * M * N;
    #pragma unroll
    for (int i = 0; i < 4; ++i) {
        int m = m0 + ty + 16 * i;
        #pragma unroll
        for (int j = 0; j < 4; ++j) {
            int n = n0 + tx + 16 * j;
            float v = acc[i][j];
            if (MODE == 0) Cz[(size_t)m * N + n] = v + ((z == 0) ? p0 * bias[n] : 0.f);
            else           Cz[(size_t)m * N + n] = (v + ((z == 0) ? bias[n] : 0.f)) * p0;
        }
    }
}

// ---- attention: scores + softmax over r + column-sum of probs ----
// kd sums the 4 ksum split-K partials; q-row staged per-wave in LDS (broadcast
// float4 reads replace the 64-step __shfl chain).
__global__ __launch_bounds__(256) void attn_kernel(const float* __restrict__ qp,
                                                   const float* __restrict__ ksum,
                                                   float* __restrict__ psum) {
    int h = blockIdx.x >> 2;
    int n = blockIdx.x & 3;
    __shared__ float kd[64][68];    // 272 B rows: 16B-aligned, conflict-free b128
    __shared__ float qs[4][68];
    __shared__ float sacc[4][64];
    int tid = threadIdx.x;

    #pragma unroll
    for (int it = 0; it < 16; ++it) {
        int idx = tid + 256 * it;
        int r = idx >> 6, d = idx & 63;
        size_t ki = (size_t)(r * 4 + n) * 768 + h * 64 + d;
        kd[r][d] = ksum[ki] + ksum[ki + 196608] + ksum[ki + 393216] + ksum[ki + 589824];
    }
    __syncthreads();

    int wave = tid >> 6, lane = tid & 63;
    float acc = 0.f;
    for (int q = wave; q < 256; q += 4) {
        size_t qi = (size_t)(q * 4 + n) * 768 + h * 64 + lane;
        float qv = qp[qi] + qp[qi + 786432];     // 2 split-K partials
        qs[wave][lane] = qv;                     // intra-wave only: no barrier needed
        float val = 0.f;
        #pragma unroll
        for (int d4 = 0; d4 < 16; ++d4) {
            float4 kv = *(const float4*)&kd[lane][d4 * 4];
            float4 qq = *(const float4*)&qs[wave][d4 * 4];
            val += qq.x * kv.x + qq.y * kv.y + qq.z * kv.z + qq.w * kv.w;
        }
        float mx = val;
        #pragma unroll
        for (int off = 1; off < 64; off <<= 1) mx = fmaxf(mx, __shfl_xor(mx, off));
        float p = __expf(val - mx);
        float s = p;
        #pragma unroll
        for (int off = 1; off < 64; off <<= 1) s += __shfl_xor(s, off);
        acc += p / s;
    }
    sacc[wave][lane] = acc;
    __syncthreads();
    if (tid < 64) {
        psum[blockIdx.x * 64 + tid] =
            sacc[0][tid] + sacc[1][tid] + sacc[2][tid] + sacc[3][tid];
    }
}

// ---- MFMA bf16 GEMM: 256x256 tile, BK=32, 8 waves (2Mx4N), 512 threads ----
// 4-slot LDS pipeline (128 KB), prefetch 3 tiles, counted vmcnt(8), XOR-swizzled
// LDS via pre-swizzled global source + swizzled ds_read, setprio, XCD swizzle.
// MODE 2: Cb = bf16((acc + bias[n]) * scale[((n>>6)*4 + (m&3))*64 + (m>>10)])
// MODE 3: Cf = acc + bias[n]

// physical short-offset of logical (row R, k-group kg) inside one 256x32 tile:
// row-pair = R>>1 (128 B, spans all 32 banks); 16B-slot within pair XOR'd by
// pair&7 -> consecutive 8 lanes of a ds_read_b128 cover all 8 slots = all banks.
__device__ __forceinline__ int swz(int R, int kg) {
    return ((R >> 1) << 6) + ((((((R & 1) << 2) | kg)) ^ ((R >> 1) & 7)) << 3);
}

template <int MODE>
__global__ __launch_bounds__(512, 2) void mfma_gemm2(const ushort* __restrict__ A,
                                                     const ushort* __restrict__ W,
                                                     const float* __restrict__ bias,
                                                     const float* __restrict__ scale,
                                                     float* __restrict__ Cf,
                                                     __hip_bfloat16* __restrict__ Cb,
                                                     int M, int N, int K) {
    __shared__ short lds[65536];        // 4 slots x (A 8192 + B 8192 shorts) = 128 KB
    const int NT = K >> 5;              // K-tiles of 32
    int tid = threadIdx.x;
    int wave = tid >> 6, lane = tid & 63;
    int wr = wave >> 2, wc = wave & 3;  // 2 x 4 wave grid
    int r16 = lane & 15, kg = lane >> 4;

    // T1: XCD-aware block swizzle (gridDim.x % 8 == 0 -> bijective)
    int cpx = gridDim.x >> 3;
    int hh = blockIdx.x;
    int orig = (hh & 7) * cpx + (hh >> 3);
    int nbx = N >> 8;
    int by = orig / nbx, bx = orig - by * nbx;
    int m0 = by << 8, n0 = bx << 8;

    // staging: 1024 chunks of 16B per 256x32 tile; thread owns chunks tid, tid+512.
    // LDS deposit is linear (wave-uniform base + lane*16); the swizzle is applied
    // by permuting the GLOBAL source (inverse == same XOR involution).
    int c0 = tid, c1 = tid + 512;
    int p0c = c0 >> 3, s0c = (c0 & 7) ^ (p0c & 7);
    int row0 = (p0c << 1) | (s0c >> 2), kg0 = s0c & 3;
    int p1c = c1 >> 3, s1c = (c1 & 7) ^ (p1c & 7);
    int row1 = (p1c << 1) | (s1c >> 2), kg1 = s1c & 3;
    const ushort* pA0 = A + (size_t)(m0 + row0) * K + kg0 * 8;
    const ushort* pA1 = A + (size_t)(m0 + row1) * K + kg1 * 8;
    const ushort* pB0 = W + (size_t)(n0 + row0) * K + kg0 * 8;
    const ushort* pB1 = W + (size_t)(n0 + row1) * K + kg1 * 8;
    int dep0 = (wave * 64) * 8;         // shorts; chunk range of this wave
    int dep1 = (512 + wave * 64) * 8;

    f32x4 acc[8][4];
    #pragma unroll
    for (int i = 0; i < 8; ++i)
        #pragma unroll
        for (int j = 0; j < 4; ++j) acc[i][j] = (f32x4){0.f, 0.f, 0.f, 0.f};

    // prologue: issue tiles 0,1,2 (4 loads each per wave) into slots 0,1,2
    #pragma unroll
    for (int p = 0; p < 3; ++p) {
        int sb = p * 16384, ko = p * 32;
        load_lds16(pA0 + ko, &lds[sb + dep0]);
        load_lds16(pA1 + ko, &lds[sb + dep1]);
        load_lds16(pB0 + ko, &lds[sb + 8192 + dep0]);
        load_lds16(pB1 + ko, &lds[sb + 8192 + dep1]);
    }

    for (int t = 0; t < NT; ++t) {
        // counted wait: tile t's 4 loads are oldest; up to 8 (tiles t+1,t+2) in flight
        if (t + 2 < NT)      { asm volatile("s_waitcnt vmcnt(8)" ::: "memory"); }
        else if (t + 1 < NT) { asm volatile("s_waitcnt vmcnt(4)" ::: "memory"); }
        else                 { asm volatile("s_waitcnt vmcnt(0)" ::: "memory"); }
        __builtin_amdgcn_s_barrier();
        __builtin_amdgcn_sched_barrier(0);
        const short* sb = &lds[(t & 3) * 16384];
        int s3 = ((t + 3) & 3) * 16384;     // slot vacated by tile t-1
        int k3 = (t + 3) * 32;

        bf16x8 bv[4], af[4];
        #pragma unroll
        for (int ni = 0; ni < 4; ++ni)
            bv[ni] = *(const bf16x8*)&sb[8192 + swz(wc * 64 + ni * 16 + r16, kg)];
        #pragma unroll
        for (int mi = 0; mi < 4; ++mi)
            af[mi] = *(const bf16x8*)&sb[swz(wr * 128 + mi * 16 + r16, kg)];
        if (t + 3 < NT) {                   // stage A-half of tile t+3
            load_lds16(pA0 + k3, &lds[s3 + dep0]);
            load_lds16(pA1 + k3, &lds[s3 + dep1]);
        }
        __builtin_amdgcn_s_setprio(1);
        #pragma unroll
        for (int mi = 0; mi < 4; ++mi)
            #pragma unroll
            for (int ni = 0; ni < 4; ++ni)
                acc[mi][ni] = __builtin_amdgcn_mfma_f32_16x16x32_bf16(
                    af[mi], bv[ni], acc[mi][ni], 0, 0, 0);
        __builtin_amdgcn_s_setprio(0);

        #pragma unroll
        for (int mi = 0; mi < 4; ++mi)
            af[mi] = *(const bf16x8*)&sb[swz(wr * 128 + 64 + mi * 16 + r16, kg)];
        if (t + 3 < NT) {                   // stage B-half of tile t+3
            load_lds16(pB0 + k3, &lds[s3 + 8192 + dep0]);
            load_lds16(pB1 + k3, &lds[s3 + 8192 + dep1]);
        }
        __builtin_amdgcn_s_setprio(1);
        #pragma unroll
        for (int mi = 0; mi < 4; ++mi)
            #pragma unroll
            for (int ni = 0; ni < 4; ++ni)
                acc[4 + mi][ni] = __builtin_amdgcn_mfma_f32_16x16x32_bf16(
                    af[mi], bv[ni], acc[4 + mi][ni], 0, 0, 0);
        __builtin_amdgcn_s_setprio(0);
    }

    // epilogue: C/D layout col=lane&15, row=(lane>>4)*4+i
    int col = lane & 15, rbase = (lane >> 4) << 2;
    #pragma unroll
    for (int ni = 0; ni < 4; ++ni) {
        int gn = n0 + wc * 64 + ni * 16 + col;
        float bn = bias[gn];
        #pragma unroll
        for (int mi = 0; mi < 8; ++mi) {
            int gmb = m0 + wr * 128 + mi * 16 + rbase;
            #pragma unroll
            for (int i = 0; i < 4; ++i) {
                int gm = gmb + i;
                float v = acc[mi][ni][i] + bn;
                if (MODE == 2) {
                    float sc = scale[(((gn >> 6) << 2) + (gm & 3)) * 64 + (gm >> 10)];
                    Cb[(size_t)gm * N + gn] = __float2bfloat16(v * sc);
                } else {
                    Cf[(size_t)gm * N + gn] = v;
                }
            }
        }
    }
}

extern "C" void kernel_launch(void* const* d_in, const int* in_sizes, int n_in,
                              void* d_out, int out_size, void* d_ws, size_t ws_size,
                              hipStream_t stream) {
    const float* x     = (const float*)d_in[0];
    const float* query = (const float*)d_in[1];
    const float* Wq    = (const float*)d_in[2];
    const float* bq    = (const float*)d_in[3];
    const float* Wk    = (const float*)d_in[4];
    const float* bk    = (const float*)d_in[5];
    const float* Wv    = (const float*)d_in[6];
    const float* bv    = (const float*)d_in[7];
    const float* Wo    = (const float*)d_in[8];
    const float* bo    = (const float*)d_in[9];
    float* out = (float*)d_out;

    // workspace layout (~205 MB)
    __hip_bfloat16* xb   = (__hip_bfloat16*)d_ws;        // 65536*768
    __hip_bfloat16* vtmp = xb + 50331648;                // 65536*768
    __hip_bfloat16* Wvb  = vtmp + 50331648;              // 768*768
    __hip_bfloat16* Wob  = Wvb + 589824;                 // 768*768
    float* ksum = (float*)(Wob + 589824);                // 4 x 256*768 (split-K)
    float* qp   = ksum + 786432;                         // 2 x 1024*768 (split-K)
    float* psum = qp + 1572864;                          // 12*4*64
    // xsum c-partials (4 x 256 x 768 fp32 = 3 MB) live in the vtmp region:
    // dead until mfma_gemm2<2> runs, consumed by gemm_kernel<0> before that.
    float* xsp = (float*)vtmp;

    // 1) merged prep: xsum partials + x->bf16 + Wv/Wo->bf16 (one launch)
    prep_kernel<<<1920, 256, 0, stream>>>(x, xsp, xb, Wv, Wvb, Wo, Wob);
    // 2) ksum partials = (sum_p xsp) @ Wk^T + 256*bk   (256x768x768, split-K x4)
    gemm_kernel<0><<<dim3(12, 4, 4), 256, 0, stream>>>(xsp, Wk, bk, ksum, 256, 768, 768, 192, 256.0f);
    // 3) qp partials = (query @ Wq^T + bq) / 128       (1024x768x512, split-K x2)
    gemm_kernel<1><<<dim3(12, 16, 2), 256, 0, stream>>>(query, Wq, bq, qp, 1024, 768, 512, 256, 0.0078125f);
    // 4) psum = sum_q softmax_r(qp . ksum)             (sums partials on load)
    attn_kernel<<<48, 256, 0, stream>>>(qp, ksum, psum);
    // 5) vtmp = bf16((xb @ Wvb^T + bv) * psum)   MFMA  (65536 x 768 x 768)
    mfma_gemm2<2><<<768, 512, 0, stream>>>(
        (const ushort*)xb, (const ushort*)Wvb, bv, psum, nullptr, vtmp, 65536, 768, 768);
    // 6) out = vtmp @ Wob^T + bo                 MFMA  (65536 x 768 x 768)
    mfma_gemm2<3><<<768, 512, 0, stream>>>(
        (const ushort*)vtmp, (const ushort*)Wob, bo, nullptr, out, nullptr, 65536, 768, 768);
}

// Round 3
// 608.814 us; speedup vs baseline: 1.3564x; 1.1133x over previous
//
#include <hip/hip_runtime.h>
#include <hip/hip_bf16.h>

// x: (R=64, C=256, B=4, E=768) fp32 ; query: (Q=256, B=4, QD=512)
// Wq: (768,512), Wk/Wv/Wo: (768,768), biases: (768,)  ; out: (R,C,B,E) fp32
// H=12, D=64, scaling = D^-0.5/sqrt(Q) = 1/128
//
// Decomposition:
//  xsum[rb,e]   = sum_c x[r,c,n,e]                       (rb = r*4+n)
//  ksum[rb,e]   = xsum @ Wk^T + 256*bk                   (split-K x4)
//  qp[qb,e]     = (query @ Wq^T + bq) / 128              (split-K x4)
//  psum[h,n,r]  = sum_q softmax_r( qp . ksum )           (split-q x4)
//  vtmp[m,e]    = bf16( (x @ Wv^T + bv) * psum[e>>6, m&3, m>>10] )
//  out[m,f]     = vtmp @ Wo^T + bo
// Big GEMMs: 256x256 tile, BK=32, 8 waves, 4-slot LDS (128KB) counted-vmcnt(8)
// pipeline, XOR-swizzled LDS both-sides, setprio, XCD swizzle, and an
// LDS-repack epilogue (16B coalesced stores instead of 128 scalar stores).

typedef __attribute__((ext_vector_type(8))) short bf16x8;
typedef __attribute__((ext_vector_type(4))) float f32x4;

__device__ __forceinline__ void load_lds16(const void* g, void* l) {
    __builtin_amdgcn_global_load_lds(
        (const __attribute__((address_space(1))) void*)g,
        (__attribute__((address_space(3))) void*)l, 16, 0, 0);
}

// ---- merged prep: xsum partials + x->bf16 (blocks 0..767),
//                   Wv->bf16 (768..1343), Wo->bf16 (1344..1919) ----
__global__ __launch_bounds__(256) void prep_kernel(const float* __restrict__ x,
                                                   float* __restrict__ xsp,
                                                   __hip_bfloat16* __restrict__ xb,
                                                   const float* __restrict__ Wv,
                                                   __hip_bfloat16* __restrict__ Wvb,
                                                   const float* __restrict__ Wo,
                                                   __hip_bfloat16* __restrict__ Wob) {
    int b = blockIdx.x, tid = threadIdx.x;
    if (b < 768) {
        int gid = b * 256 + tid;                 // 0 .. 196607
        int e4 = gid % 192;                      // e / 4
        int t2 = gid / 192;                      // 0 .. 1023
        int rb = t2 & 255;                       // r*4+n
        int part = t2 >> 8;                      // c-chunk 0..3
        int r = rb >> 2, n = rb & 3;
        size_t base = (size_t)r * 786432 + (size_t)part * 196608 + n * 768 + e4 * 4;
        const float4* px = (const float4*)(x + base);
        ushort* xbu = (ushort*)xb + base;
        float4 s = {0.f, 0.f, 0.f, 0.f};
        #pragma unroll 4
        for (int c = 0; c < 64; ++c) {
            float4 v = px[(size_t)c * 768];
            s.x += v.x; s.y += v.y; s.z += v.z; s.w += v.w;
            union { ushort4 u; __hip_bfloat16 h[4]; } pk;
            pk.h[0] = __float2bfloat16(v.x); pk.h[1] = __float2bfloat16(v.y);
            pk.h[2] = __float2bfloat16(v.z); pk.h[3] = __float2bfloat16(v.w);
            *(ushort4*)(xbu + (size_t)c * 3072) = pk.u;
        }
        *(float4*)(xsp + (size_t)part * 196608 + rb * 768 + e4 * 4) = s;
    } else {
        const float* src = (b < 1344) ? Wv : Wo;
        __hip_bfloat16* dst = (b < 1344) ? Wvb : Wob;
        int i = (b - ((b < 1344) ? 768 : 1344)) * 256 + tid;   // 0..147455 float4s
        float4 v = ((const float4*)src)[i];
        dst[i * 4 + 0] = __float2bfloat16(v.x);
        dst[i * 4 + 1] = __float2bfloat16(v.y);
        dst[i * 4 + 2] = __float2bfloat16(v.z);
        dst[i * 4 + 3] = __float2bfloat16(v.w);
    }
}

// ---- small fp32 GEMM with split-K (blockIdx.z): partial z covers K-range
// [z*KS, (z+1)*KS); partial z written to Cf + z*M*N. bias applied in z==0 only.
// MODE 0: A is 4 c-partials (stride 196608) summed on load; +p0*bias
// MODE 1: *p0 epilogue, +bias inside
template <int MODE>
__global__ __launch_bounds__(256) void gemm_kernel(const float* __restrict__ A,
                                                   const float* __restrict__ W,
                                                   const float* __restrict__ bias,
                                                   float* __restrict__ Cf,
                                                   int M, int N, int K, int KS, float p0) {
    __shared__ float As[16][65];
    __shared__ float Ws[16][65];
    int tid = threadIdx.x;
    int tx = tid & 15, ty = tid >> 4;
    int m0 = blockIdx.y * 64, n0 = blockIdx.x * 64;
    int z = blockIdx.z;
    int kbeg = z * KS, kend = kbeg + KS;
    float acc[4][4] = {};

    for (int k0 = kbeg; k0 < kend; k0 += 16) {
        #pragma unroll
        for (int i = 0; i < 4; ++i) {
            int idx = tid + 256 * i;
            int mm = idx >> 4, kk = idx & 15;
            size_t ai = (size_t)(m0 + mm) * K + k0 + kk;
            if (MODE == 0)
                As[kk][mm] = A[ai] + A[ai + 196608] + A[ai + 393216] + A[ai + 589824];
            else
                As[kk][mm] = A[ai];
            Ws[kk][mm] = W[(size_t)(n0 + mm) * K + k0 + kk];
        }
        __syncthreads();
        #pragma unroll
        for (int kk = 0; kk < 16; ++kk) {
            float a[4], b[4];
            #pragma unroll
            for (int i = 0; i < 4; ++i) a[i] = As[kk][ty + 16 * i];
            #pragma unroll
            for (int j = 0; j < 4; ++j) b[j] = Ws[kk][tx + 16 * j];
            #pragma unroll
            for (int i = 0; i < 4; ++i)
                #pragma unroll
                for (int j = 0; j < 4; ++j) acc[i][j] += a[i] * b[j];
        }
        __syncthreads();
    }
    float* Cz = Cf + (size_t)z * M * N;
    #pragma unroll
    for (int i = 0; i < 4; ++i) {
        int m = m0 + ty + 16 * i;
        #pragma unroll
        for (int j = 0; j < 4; ++j) {
            int n = n0 + tx + 16 * j;
            float v = acc[i][j];
            if (MODE == 0) Cz[(size_t)m * N + n] = v + ((z == 0) ? p0 * bias[n] : 0.f);
            else           Cz[(size_t)m * N + n] = (v + ((z == 0) ? bias[n] : 0.f)) * p0;
        }
    }
}

// ---- attention: scores + softmax over r + column-sum of probs ----
// grid = 192: blockIdx.x = qpart*48 + (h*4+n); each block covers 64 q's.
// psum partials [qpart][48][64] summed in mfma_gemm2<2>'s epilogue.
__global__ __launch_bounds__(256) void attn_kernel(const float* __restrict__ qp,
                                                   const float* __restrict__ ksum,
                                                   float* __restrict__ psum) {
    int qpart = blockIdx.x / 48;
    int hn = blockIdx.x % 48;
    int h = hn >> 2;
    int n = hn & 3;
    __shared__ float kd[64][68];    // 272 B rows: 16B-aligned, conflict-free b128
    __shared__ float qs[4][68];
    __shared__ float sacc[4][64];
    int tid = threadIdx.x;

    #pragma unroll
    for (int it = 0; it < 16; ++it) {
        int idx = tid + 256 * it;
        int r = idx >> 6, d = idx & 63;
        size_t ki = (size_t)(r * 4 + n) * 768 + h * 64 + d;
        kd[r][d] = ksum[ki] + ksum[ki + 196608] + ksum[ki + 393216] + ksum[ki + 589824];
    }
    __syncthreads();

    int wave = tid >> 6, lane = tid & 63;
    float acc = 0.f;
    for (int q = qpart * 64 + wave; q < qpart * 64 + 64; q += 4) {
        size_t qi = (size_t)(q * 4 + n) * 768 + h * 64 + lane;
        float qv = qp[qi] + qp[qi + 786432] + qp[qi + 1572864] + qp[qi + 2359296];
        qs[wave][lane] = qv;                     // intra-wave only: no barrier needed
        float val = 0.f;
        #pragma unroll
        for (int d4 = 0; d4 < 16; ++d4) {
            float4 kv = *(const float4*)&kd[lane][d4 * 4];
            float4 qq = *(const float4*)&qs[wave][d4 * 4];
            val += qq.x * kv.x + qq.y * kv.y + qq.z * kv.z + qq.w * kv.w;
        }
        float mx = val;
        #pragma unroll
        for (int off = 1; off < 64; off <<= 1) mx = fmaxf(mx, __shfl_xor(mx, off));
        float p = __expf(val - mx);
        float s = p;
        #pragma unroll
        for (int off = 1; off < 64; off <<= 1) s += __shfl_xor(s, off);
        acc += p / s;
    }
    sacc[wave][lane] = acc;
    __syncthreads();
    if (tid < 64) {
        psum[blockIdx.x * 64 + tid] =
            sacc[0][tid] + sacc[1][tid] + sacc[2][tid] + sacc[3][tid];
    }
}

// ---- MFMA bf16 GEMM: 256x256 tile, BK=32, 8 waves (2Mx4N), 512 threads ----
// MODE 2: Cb = bf16((acc + bias[n]) * sum_qp psum[qp][((n>>6)*4+(m&3))*64+(m>>10)])
// MODE 3: Cf = acc + bias[n]
// Epilogue repacks through LDS -> 16B coalesced stores.

// physical short-offset of logical (row R, k-group kg) inside one 256x32 tile.
__device__ __forceinline__ int swz(int R, int kg) {
    return ((R >> 1) << 6) + ((((((R & 1) << 2) | kg)) ^ ((R >> 1) & 7)) << 3);
}

template <int MODE>
__global__ __launch_bounds__(512, 2) void mfma_gemm2(const ushort* __restrict__ A,
                                                     const ushort* __restrict__ W,
                                                     const float* __restrict__ bias,
                                                     const float* __restrict__ scale,
                                                     float* __restrict__ Cf,
                                                     __hip_bfloat16* __restrict__ Cb,
                                                     int M, int N, int K) {
    __shared__ short lds[65536];        // 4 slots x (A 8192 + B 8192 shorts) = 128 KB
    const int NT = K >> 5;              // K-tiles of 32
    int tid = threadIdx.x;
    int wave = tid >> 6, lane = tid & 63;
    int wr = wave >> 2, wc = wave & 3;  // 2 x 4 wave grid
    int r16 = lane & 15, kg = lane >> 4;

    // T1: XCD-aware block swizzle (gridDim.x % 8 == 0 -> bijective)
    int cpx = gridDim.x >> 3;
    int hh = blockIdx.x;
    int orig = (hh & 7) * cpx + (hh >> 3);
    int nbx = N >> 8;
    int by = orig / nbx, bx = orig - by * nbx;
    int m0 = by << 8, n0 = bx << 8;

    // staging: 1024 chunks of 16B per 256x32 tile; thread owns chunks tid, tid+512.
    // LDS deposit is linear; swizzle applied by permuting the GLOBAL source.
    int c0 = tid, c1 = tid + 512;
    int p0c = c0 >> 3, s0c = (c0 & 7) ^ (p0c & 7);
    int row0 = (p0c << 1) | (s0c >> 2), kg0 = s0c & 3;
    int p1c = c1 >> 3, s1c = (c1 & 7) ^ (p1c & 7);
    int row1 = (p1c << 1) | (s1c >> 2), kg1 = s1c & 3;
    const ushort* pA0 = A + (size_t)(m0 + row0) * K + kg0 * 8;
    const ushort* pA1 = A + (size_t)(m0 + row1) * K + kg1 * 8;
    const ushort* pB0 = W + (size_t)(n0 + row0) * K + kg0 * 8;
    const ushort* pB1 = W + (size_t)(n0 + row1) * K + kg1 * 8;
    int dep0 = (wave * 64) * 8;         // shorts; chunk range of this wave
    int dep1 = (512 + wave * 64) * 8;

    f32x4 acc[8][4];
    #pragma unroll
    for (int i = 0; i < 8; ++i)
        #pragma unroll
        for (int j = 0; j < 4; ++j) acc[i][j] = (f32x4){0.f, 0.f, 0.f, 0.f};

    // prologue: issue tiles 0,1,2 into slots 0,1,2
    #pragma unroll
    for (int p = 0; p < 3; ++p) {
        int sb = p * 16384, ko = p * 32;
        load_lds16(pA0 + ko, &lds[sb + dep0]);
        load_lds16(pA1 + ko, &lds[sb + dep1]);
        load_lds16(pB0 + ko, &lds[sb + 8192 + dep0]);
        load_lds16(pB1 + ko, &lds[sb + 8192 + dep1]);
    }

    for (int t = 0; t < NT; ++t) {
        // counted wait: tile t's 4 loads oldest; up to 8 (tiles t+1,t+2) in flight
        if (t + 2 < NT)      { asm volatile("s_waitcnt vmcnt(8)" ::: "memory"); }
        else if (t + 1 < NT) { asm volatile("s_waitcnt vmcnt(4)" ::: "memory"); }
        else                 { asm volatile("s_waitcnt vmcnt(0)" ::: "memory"); }
        __builtin_amdgcn_s_barrier();
        __builtin_amdgcn_sched_barrier(0);
        const short* sb = &lds[(t & 3) * 16384];
        int s3 = ((t + 3) & 3) * 16384;     // slot vacated by tile t-1
        int k3 = (t + 3) * 32;

        if (t + 3 < NT) {                   // issue-early: stage tile t+3 now
            load_lds16(pA0 + k3, &lds[s3 + dep0]);
            load_lds16(pA1 + k3, &lds[s3 + dep1]);
            load_lds16(pB0 + k3, &lds[s3 + 8192 + dep0]);
            load_lds16(pB1 + k3, &lds[s3 + 8192 + dep1]);
        }

        bf16x8 bv[4], af[4];
        #pragma unroll
        for (int ni = 0; ni < 4; ++ni)
            bv[ni] = *(const bf16x8*)&sb[8192 + swz(wc * 64 + ni * 16 + r16, kg)];
        #pragma unroll
        for (int mi = 0; mi < 4; ++mi)
            af[mi] = *(const bf16x8*)&sb[swz(wr * 128 + mi * 16 + r16, kg)];
        __builtin_amdgcn_s_setprio(1);
        #pragma unroll
        for (int mi = 0; mi < 4; ++mi)
            #pragma unroll
            for (int ni = 0; ni < 4; ++ni)
                acc[mi][ni] = __builtin_amdgcn_mfma_f32_16x16x32_bf16(
                    af[mi], bv[ni], acc[mi][ni], 0, 0, 0);
        __builtin_amdgcn_s_setprio(0);

        #pragma unroll
        for (int mi = 0; mi < 4; ++mi)
            af[mi] = *(const bf16x8*)&sb[swz(wr * 128 + 64 + mi * 16 + r16, kg)];
        __builtin_amdgcn_s_setprio(1);
        #pragma unroll
        for (int mi = 0; mi < 4; ++mi)
            #pragma unroll
            for (int ni = 0; ni < 4; ++ni)
                acc[4 + mi][ni] = __builtin_amdgcn_mfma_f32_16x16x32_bf16(
                    af[mi], bv[ni], acc[4 + mi][ni], 0, 0, 0);
        __builtin_amdgcn_s_setprio(0);
    }

    // ---- epilogue: bias/scale in-register, repack via LDS, 16B coalesced stores
    // C/D layout: col=lane&15, row=(lane>>4)*4+i
    int col = lane & 15, rq = lane >> 4;

    if (MODE == 2) {
        __syncthreads();                 // all K-loop LDS reads done before overwrite
        __hip_bfloat16* eb = (__hip_bfloat16*)lds;   // 256x256 bf16 = 128 KB
        #pragma unroll
        for (int ni = 0; ni < 4; ++ni) {
            int lgn = wc * 64 + ni * 16 + col;
            int gn = n0 + lgn;
            float bn = bias[gn];
            #pragma unroll
            for (int mi = 0; mi < 8; ++mi) {
                #pragma unroll
                for (int i = 0; i < 4; ++i) {
                    int lr = wr * 128 + mi * 16 + rq * 4 + i;
                    int gm = m0 + lr;
                    int si = (((gn >> 6) << 2) + (gm & 3)) * 64 + (gm >> 10);
                    float sc = scale[si] + scale[si + 3072] +
                               scale[si + 6144] + scale[si + 9216];
                    float v = (acc[mi][ni][i] + bn) * sc;
                    // bank XOR: row-group spread across 8-bank groups
                    eb[lr * 256 + (lgn ^ (((lr >> 2) & 3) << 4))] = __float2bfloat16(v);
                }
            }
        }
        __syncthreads();
        #pragma unroll
        for (int it = 0; it < 16; ++it) {
            int c = it * 512 + tid;                 // 0..8191 chunks of 8 ushort
            int row = c >> 5, cc = c & 31;
            int pc = cc ^ (((row >> 2) & 3) << 1);  // chunk-unit XOR (same involution)
            bf16x8 vv = *(const bf16x8*)&lds[row * 256 + pc * 8];
            *(bf16x8*)(void*)&Cb[(size_t)(m0 + row) * N + n0 + cc * 8] = vv;
        }
    } else {
        float* ef = (float*)lds;                    // 128x256 fp32 = 128 KB per pass
        #pragma unroll
        for (int p = 0; p < 2; ++p) {
            __syncthreads();
            if (wr == p) {
                #pragma unroll
                for (int ni = 0; ni < 4; ++ni) {
                    int lgn = wc * 64 + ni * 16 + col;
                    float bn = bias[n0 + lgn];
                    #pragma unroll
                    for (int mi = 0; mi < 8; ++mi) {
                        #pragma unroll
                        for (int i = 0; i < 4; ++i) {
                            int lr = mi * 16 + rq * 4 + i;      // 0..127
                            float v = acc[mi][ni][i] + bn;
                            ef[lr * 256 + (lgn ^ (((lr >> 2) & 3) << 4))] = v;
                        }
                    }
                }
            }
            __syncthreads();
            #pragma unroll
            for (int it = 0; it < 16; ++it) {
                int c = it * 512 + tid;                 // 0..8191 chunks of 4 floats
                int row = c >> 6, cc = c & 63;
                int pc = cc ^ (((row >> 2) & 3) << 2);
                float4 vv = *(const float4*)&ef[row * 256 + pc * 4];
                *(float4*)&Cf[(size_t)(m0 + p * 128 + row) * N + n0 + cc * 4] = vv;
            }
        }
    }
}

extern "C" void kernel_launch(void* const* d_in, const int* in_sizes, int n_in,
                              void* d_out, int out_size, void* d_ws, size_t ws_size,
                              hipStream_t stream) {
    const float* x     = (const float*)d_in[0];
    const float* query = (const float*)d_in[1];
    const float* Wq    = (const float*)d_in[2];
    const float* bq    = (const float*)d_in[3];
    const float* Wk    = (const float*)d_in[4];
    const float* bk    = (const float*)d_in[5];
    const float* Wv    = (const float*)d_in[6];
    const float* bv    = (const float*)d_in[7];
    const float* Wo    = (const float*)d_in[8];
    const float* bo    = (const float*)d_in[9];
    float* out = (float*)d_out;

    // workspace layout (~220 MB)
    __hip_bfloat16* xb   = (__hip_bfloat16*)d_ws;        // 65536*768
    __hip_bfloat16* vtmp = xb + 50331648;                // 65536*768
    __hip_bfloat16* Wvb  = vtmp + 50331648;              // 768*768
    __hip_bfloat16* Wob  = Wvb + 589824;                 // 768*768
    float* ksum = (float*)(Wob + 589824);                // 4 x 256*768  (split-K)
    float* qp   = ksum + 786432;                         // 4 x 1024*768 (split-K)
    float* psum = qp + 3145728;                          // 4 x 12*4*64  (split-q)
    // xsum c-partials (4 x 256 x 768 fp32 = 3 MB) live in the vtmp region:
    // dead until mfma_gemm2<2> runs, consumed by gemm_kernel<0> before that.
    float* xsp = (float*)vtmp;

    // 1) merged prep: xsum partials + x->bf16 + Wv/Wo->bf16 (one launch)
    prep_kernel<<<1920, 256, 0, stream>>>(x, xsp, xb, Wv, Wvb, Wo, Wob);
    // 2) ksum partials = (sum_p xsp) @ Wk^T + 256*bk   (256x768x768, split-K x4)
    gemm_kernel<0><<<dim3(12, 4, 4), 256, 0, stream>>>(xsp, Wk, bk, ksum, 256, 768, 768, 192, 256.0f);
    // 3) qp partials = (query @ Wq^T + bq) / 128       (1024x768x512, split-K x4)
    gemm_kernel<1><<<dim3(12, 16, 4), 256, 0, stream>>>(query, Wq, bq, qp, 1024, 768, 512, 128, 0.0078125f);
    // 4) psum partials = sum_q softmax_r(qp . ksum)    (split-q x4)
    attn_kernel<<<192, 256, 0, stream>>>(qp, ksum, psum);
    // 5) vtmp = bf16((xb @ Wvb^T + bv) * psum)   MFMA  (65536 x 768 x 768)
    mfma_gemm2<2><<<768, 512, 0, stream>>>(
        (const ushort*)xb, (const ushort*)Wvb, bv, psum, nullptr, vtmp, 65536, 768, 768);
    // 6) out = vtmp @ Wob^T + bo                 MFMA  (65536 x 768 x 768)
    mfma_gemm2<3><<<768, 512, 0, stream>>>(
        (const ushort*)vtmp, (const ushort*)Wob, bo, nullptr, out, nullptr, 65536, 768, 768);
}